// Round 3
// baseline (2612.772 us; speedup 1.0000x reference)
//
#include <hip/hip_runtime.h>
#include <hip/hip_bf16.h>
#include <math.h>

// Problem constants (from reference)
#define T_SEQ 1536
#define CDIM  1536
#define HEADS 8
#define DK    64
#define DV    192
#define RWIN  (2 * T_SEQ - 1)   // 3071
#define QI    4                 // query rows per attention block

// ---------------------------------------------------------------------------
// Generic fp32 GEMM: C[M,N] = scale * (A[M,Kd] @ B[Kd,N]) (+ bias[n])
// Tile 128x128, BK=8, 256 threads, 8x8 micro-tile as 2x2 of float4 blocks.
// Register-prefetch pipeline: LDS-write(cur) -> barrier -> issue loads(next)
// -> compute(cur); the vmcnt wait lands after ~512 FMAs of cover.
// All dims are multiples of tile sizes (M=3072, N in {512,1536}, Kd=1536).
// ---------------------------------------------------------------------------
#define BM 128
#define BN 128
#define BK 8

__global__ __launch_bounds__(256) void gemm_kernel(
    const float* __restrict__ A, const float* __restrict__ B,
    float* __restrict__ C, int M, int N, int Kd, float scale,
    const float* __restrict__ bias)
{
  __shared__ float As[BK][BM + 4];   // transposed: As[kk][m]; +4 pad keeps f4 align
  __shared__ float Bs[BK][BN];       // Bs[kk][n]
  const int tid = threadIdx.x;
  const int tx = tid & 15;
  const int ty = tid >> 4;
  const int m0 = blockIdx.x * BM;
  const int n0 = blockIdx.y * BN;

  const int a_m = tid >> 1;          // 0..127
  const int a_k = (tid & 1) * 4;     // 0 or 4
  const int b_k = tid >> 5;          // 0..7
  const int b_n = (tid & 31) * 4;    // 0..124

  float acc[8][8];
  #pragma unroll
  for (int i = 0; i < 8; ++i)
    #pragma unroll
    for (int j = 0; j < 8; ++j) acc[i][j] = 0.f;

  // prologue: load first K-tile into registers
  float4 a4 = *reinterpret_cast<const float4*>(&A[(size_t)(m0 + a_m) * Kd + a_k]);
  float4 b4 = *reinterpret_cast<const float4*>(&B[(size_t)b_k * N + n0 + b_n]);

  for (int k0 = 0; k0 < Kd; k0 += BK) {
    __syncthreads();                 // previous iteration's LDS reads complete
    As[a_k + 0][a_m] = a4.x;
    As[a_k + 1][a_m] = a4.y;
    As[a_k + 2][a_m] = a4.z;
    As[a_k + 3][a_m] = a4.w;
    *reinterpret_cast<float4*>(&Bs[b_k][b_n]) = b4;
    __syncthreads();
    if (k0 + BK < Kd) {              // issue next tile's loads before compute
      a4 = *reinterpret_cast<const float4*>(&A[(size_t)(m0 + a_m) * Kd + k0 + BK + a_k]);
      b4 = *reinterpret_cast<const float4*>(&B[(size_t)(k0 + BK + b_k) * N + n0 + b_n]);
    }
    #pragma unroll
    for (int kk = 0; kk < BK; ++kk) {
      float4 alo = *reinterpret_cast<const float4*>(&As[kk][ty * 4]);
      float4 ahi = *reinterpret_cast<const float4*>(&As[kk][64 + ty * 4]);
      float4 blo = *reinterpret_cast<const float4*>(&Bs[kk][tx * 4]);
      float4 bhi = *reinterpret_cast<const float4*>(&Bs[kk][64 + tx * 4]);
      float av[8] = {alo.x, alo.y, alo.z, alo.w, ahi.x, ahi.y, ahi.z, ahi.w};
      float bv[8] = {blo.x, blo.y, blo.z, blo.w, bhi.x, bhi.y, bhi.z, bhi.w};
      #pragma unroll
      for (int i = 0; i < 8; ++i)
        #pragma unroll
        for (int j = 0; j < 8; ++j)
          acc[i][j] = fmaf(av[i], bv[j], acc[i][j]);
    }
  }
  #pragma unroll
  for (int i = 0; i < 8; ++i) {
    int m = m0 + ((i >> 2) * 64) + ty * 4 + (i & 3);
    #pragma unroll
    for (int jh = 0; jh < 2; ++jh) {
      int n = n0 + jh * 64 + tx * 4;
      float4 r;
      r.x = acc[i][jh * 4 + 0] * scale;
      r.y = acc[i][jh * 4 + 1] * scale;
      r.z = acc[i][jh * 4 + 2] * scale;
      r.w = acc[i][jh * 4 + 3] * scale;
      if (bias != nullptr) {
        r.x += bias[n + 0];
        r.y += bias[n + 1];
        r.z += bias[n + 2];
        r.w += bias[n + 3];
      }
      *reinterpret_cast<float4*>(&C[(size_t)m * N + n]) = r;
    }
  }
}

// ---------------------------------------------------------------------------
// r_k[h][r][kk] = sum_f pos[r,f] * Wrk[f, h*64+kk]
// pos features analytic: emb[j] = (widths[j] > |d|), d = r-(T-1),
// widths[j] = pow_rate^(j+1)-1, pow_rate = exp(log(T+1)/32).
// Widths evaluated in double; all 32 true widths are >=0.01 from any integer
// (checked by enumeration), so the 0/1 features provably match the fp32 ref.
// ---------------------------------------------------------------------------
__global__ __launch_bounds__(512) void rk_kernel(
    const float* __restrict__ Wrk, float* __restrict__ rk)
{
  const int r = blockIdx.x;          // 0..3070
  const int t = threadIdx.x;         // 0..511
  __shared__ float pos[2 * 32];      // 64 positional features

  if (t < 64) {
    const double d = (double)(r - (T_SEQ - 1));
    const int j = t & 31;
    const double pr = exp(log((double)(T_SEQ + 1)) / 32.0);
    const double w = pow(pr, (double)(j + 1)) - 1.0;
    const float emb = (w > fabs(d)) ? 1.0f : 0.0f;
    const float sgn = (d > 0.0) ? 1.f : ((d < 0.0) ? -1.f : 0.f);
    pos[t] = (t < 32) ? emb : sgn * emb;
  }
  __syncthreads();

  float acc = 0.f;
  #pragma unroll 8
  for (int f = 0; f < 64; ++f) acc = fmaf(pos[f], Wrk[f * (HEADS * DK) + t], acc);

  const int h = t >> 6, kk = t & 63;
  rk[((size_t)h * RWIN + r) * DK + kk] = acc;
}

// ---------------------------------------------------------------------------
// Fused attention. Block = (i-tile of QI=4 rows, h, b); 256 threads.
// logits[i,j] = (q_i+rwb)·k_j + (q_i+rrb)·rk[j-i+T-1]  (relative_shift collapsed:
// verified relative_shift(x)[i,j] == x[i, j-i+T-1] by trace).
// Phases: content scores -> rel scores -> softmax (wave/row) -> PV (2-D split:
// wave owns a j-quarter, lane owns 3 V channels, LDS partial reduce).
// ---------------------------------------------------------------------------
__global__ __launch_bounds__(256) void attn_kernel(
    const float* __restrict__ q, const float* __restrict__ kbuf,
    const float* __restrict__ vbuf, const float* __restrict__ rkbuf,
    const float* __restrict__ rwb, const float* __restrict__ rrb,
    float* __restrict__ outbuf)
{
  const int it = blockIdx.x, h = blockIdx.y, b = blockIdx.z;
  const int i0 = it * QI;
  const int tid = threadIdx.x;

  __shared__ float qw[QI][DK];
  __shared__ float qr[QI][DK];
  __shared__ float sc[QI][T_SEQ];        // 24 KB
  __shared__ float part[4][QI][DV];      // 12 KB PV partials
  __shared__ float rinv[QI];

  if (tid < QI * DK) {
    const int row = tid >> 6, kk = tid & 63;
    const float qv = q[(size_t)(b * T_SEQ + i0 + row) * (HEADS * DK) + h * DK + kk];
    qw[row][kk] = qv + rwb[h * DK + kk];
    qr[row][kk] = qv + rrb[h * DK + kk];
  }
  __syncthreads();

  // ---- content: thread owns column j, computes all 4 rows (float4 k loads) ----
  for (int jt = 0; jt < T_SEQ / 256; ++jt) {
    const int j = jt * 256 + tid;
    const float4* krow = reinterpret_cast<const float4*>(
        &kbuf[(size_t)(b * T_SEQ + j) * (HEADS * DK) + h * DK]);
    float a0 = 0, a1 = 0, a2 = 0, a3 = 0;
    #pragma unroll
    for (int kq = 0; kq < DK / 4; ++kq) {
      const float4 kv = krow[kq];
      const float4 q0 = *reinterpret_cast<const float4*>(&qw[0][kq * 4]);
      const float4 q1 = *reinterpret_cast<const float4*>(&qw[1][kq * 4]);
      const float4 q2 = *reinterpret_cast<const float4*>(&qw[2][kq * 4]);
      const float4 q3 = *reinterpret_cast<const float4*>(&qw[3][kq * 4]);
      a0 = fmaf(q0.x, kv.x, fmaf(q0.y, kv.y, fmaf(q0.z, kv.z, fmaf(q0.w, kv.w, a0))));
      a1 = fmaf(q1.x, kv.x, fmaf(q1.y, kv.y, fmaf(q1.z, kv.z, fmaf(q1.w, kv.w, a1))));
      a2 = fmaf(q2.x, kv.x, fmaf(q2.y, kv.y, fmaf(q2.z, kv.z, fmaf(q2.w, kv.w, a2))));
      a3 = fmaf(q3.x, kv.x, fmaf(q3.y, kv.y, fmaf(q3.z, kv.z, fmaf(q3.w, kv.w, a3))));
    }
    sc[0][j] = a0; sc[1][j] = a1; sc[2][j] = a2; sc[3][j] = a3;
  }
  __syncthreads();

  // ---- rel: thread owns r-window index rt, reuses rk row across 4 query rows.
  // r = (T-1)-(i0+QI-1)+rt ; row i0+row reads it at j = rt-(QI-1)+row.
  const int WIN = T_SEQ + QI - 1;    // 1539
  for (int rt = tid; rt < WIN; rt += 256) {
    const int rr = (T_SEQ - 1) - (i0 + QI - 1) + rt;
    const float4* rkrow = reinterpret_cast<const float4*>(
        &rkbuf[((size_t)h * RWIN + rr) * DK]);
    float a0 = 0, a1 = 0, a2 = 0, a3 = 0;
    #pragma unroll
    for (int kq = 0; kq < DK / 4; ++kq) {
      const float4 rv = rkrow[kq];
      const float4 q0 = *reinterpret_cast<const float4*>(&qr[0][kq * 4]);
      const float4 q1 = *reinterpret_cast<const float4*>(&qr[1][kq * 4]);
      const float4 q2 = *reinterpret_cast<const float4*>(&qr[2][kq * 4]);
      const float4 q3 = *reinterpret_cast<const float4*>(&qr[3][kq * 4]);
      a0 = fmaf(q0.x, rv.x, fmaf(q0.y, rv.y, fmaf(q0.z, rv.z, fmaf(q0.w, rv.w, a0))));
      a1 = fmaf(q1.x, rv.x, fmaf(q1.y, rv.y, fmaf(q1.z, rv.z, fmaf(q1.w, rv.w, a1))));
      a2 = fmaf(q2.x, rv.x, fmaf(q2.y, rv.y, fmaf(q2.z, rv.z, fmaf(q2.w, rv.w, a2))));
      a3 = fmaf(q3.x, rv.x, fmaf(q3.y, rv.y, fmaf(q3.z, rv.z, fmaf(q3.w, rv.w, a3))));
    }
    const int jb = rt - (QI - 1);
    if (jb + 0 >= 0 && jb + 0 < T_SEQ) sc[0][jb + 0] += a0;
    if (jb + 1 >= 0 && jb + 1 < T_SEQ) sc[1][jb + 1] += a1;
    if (jb + 2 >= 0 && jb + 2 < T_SEQ) sc[2][jb + 2] += a2;
    if (jb + 3 >= 0 && jb + 3 < T_SEQ) sc[3][jb + 3] += a3;
  }
  __syncthreads();

  // ---- softmax: wave w handles row w ----
  {
    const int row = tid >> 6, lane = tid & 63;
    float m = -INFINITY;
    for (int j = lane; j < T_SEQ; j += 64) m = fmaxf(m, sc[row][j]);
    #pragma unroll
    for (int off = 32; off; off >>= 1) m = fmaxf(m, __shfl_xor(m, off));
    float s = 0.f;
    for (int j = lane; j < T_SEQ; j += 64) {
      const float e = __expf(sc[row][j] - m);
      sc[row][j] = e;
      s += e;
    }
    #pragma unroll
    for (int off = 32; off; off >>= 1) s += __shfl_xor(s, off);
    if (lane == 0) rinv[row] = 1.f / s;
  }
  __syncthreads();

  // ---- PV: wave w owns j-quarter, lane owns 3 consecutive V channels ----
  {
    const int w = tid >> 6, lane = tid & 63;
    const int jq = T_SEQ / 4;          // 384
    const int j0 = w * jq;
    const int ch = lane * 3;           // 0..189
    const float* vbase = &vbuf[(size_t)(b * T_SEQ + j0) * (HEADS * DV) + h * DV + ch];
    float a00 = 0, a01 = 0, a02 = 0;
    float a10 = 0, a11 = 0, a12 = 0;
    float a20 = 0, a21 = 0, a22 = 0;
    float a30 = 0, a31 = 0, a32 = 0;
    for (int jj = 0; jj < jq; jj += 4) {
      const float4 p0 = *reinterpret_cast<const float4*>(&sc[0][j0 + jj]);
      const float4 p1 = *reinterpret_cast<const float4*>(&sc[1][j0 + jj]);
      const float4 p2 = *reinterpret_cast<const float4*>(&sc[2][j0 + jj]);
      const float4 p3 = *reinterpret_cast<const float4*>(&sc[3][j0 + jj]);
      #pragma unroll
      for (int u = 0; u < 4; ++u) {
        const float* vp = vbase + (size_t)(jj + u) * (HEADS * DV);
        const float v0 = vp[0], v1 = vp[1], v2 = vp[2];
        const float w0 = (u == 0) ? p0.x : (u == 1) ? p0.y : (u == 2) ? p0.z : p0.w;
        const float w1 = (u == 0) ? p1.x : (u == 1) ? p1.y : (u == 2) ? p1.z : p1.w;
        const float w2 = (u == 0) ? p2.x : (u == 1) ? p2.y : (u == 2) ? p2.z : p2.w;
        const float w3 = (u == 0) ? p3.x : (u == 1) ? p3.y : (u == 2) ? p3.z : p3.w;
        a00 = fmaf(w0, v0, a00); a01 = fmaf(w0, v1, a01); a02 = fmaf(w0, v2, a02);
        a10 = fmaf(w1, v0, a10); a11 = fmaf(w1, v1, a11); a12 = fmaf(w1, v2, a12);
        a20 = fmaf(w2, v0, a20); a21 = fmaf(w2, v1, a21); a22 = fmaf(w2, v2, a22);
        a30 = fmaf(w3, v0, a30); a31 = fmaf(w3, v1, a31); a32 = fmaf(w3, v2, a32);
      }
    }
    part[w][0][ch + 0] = a00; part[w][0][ch + 1] = a01; part[w][0][ch + 2] = a02;
    part[w][1][ch + 0] = a10; part[w][1][ch + 1] = a11; part[w][1][ch + 2] = a12;
    part[w][2][ch + 0] = a20; part[w][2][ch + 1] = a21; part[w][2][ch + 2] = a22;
    part[w][3][ch + 0] = a30; part[w][3][ch + 1] = a31; part[w][3][ch + 2] = a32;
  }
  __syncthreads();

  for (int o = tid; o < QI * DV; o += 256) {
    const int r = o / DV, c = o % DV;
    const float s = part[0][r][c] + part[1][r][c] + part[2][r][c] + part[3][r][c];
    outbuf[(size_t)(b * T_SEQ + i0 + r) * (HEADS * DV) + h * DV + c] = s * rinv[r];
  }
}

// ---------------------------------------------------------------------------
extern "C" void kernel_launch(void* const* d_in, const int* in_sizes, int n_in,
                              void* d_out, int out_size, void* d_ws, size_t ws_size,
                              hipStream_t stream) {
  const float* x   = (const float*)d_in[0];  // [2,1536,1536]
  const float* Wq  = (const float*)d_in[1];  // [1536,512]
  const float* Wk  = (const float*)d_in[2];  // [1536,512]
  const float* Wv  = (const float*)d_in[3];  // [1536,1536]
  const float* Wrk = (const float*)d_in[4];  // [64,512]
  const float* rwb = (const float*)d_in[5];  // [512]
  const float* rrb = (const float*)d_in[6];  // [512]
  const float* Wo  = (const float*)d_in[7];  // [1536,1536]
  const float* bo  = (const float*)d_in[8];  // [1536]
  float* out = (float*)d_out;                // [2,1536,1536]

  const int BT = 2 * T_SEQ;                  // 3072 rows

  // workspace layout (floats): q, k, v, rk, attn  (~56.6 MB total)
  float* q    = (float*)d_ws;
  float* kbuf = q    + (size_t)BT * (HEADS * DK);
  float* vbuf = kbuf + (size_t)BT * (HEADS * DK);
  float* rkb  = vbuf + (size_t)BT * (HEADS * DV);
  float* attn = rkb  + (size_t)HEADS * RWIN * DK;

  // q/k/v projections (q scaled by K^-0.5 = 0.125; biases added in attn kernel)
  gemm_kernel<<<dim3(BT / BM, (HEADS * DK) / BN), 256, 0, stream>>>(
      x, Wq, q, BT, HEADS * DK, CDIM, 0.125f, nullptr);
  gemm_kernel<<<dim3(BT / BM, (HEADS * DK) / BN), 256, 0, stream>>>(
      x, Wk, kbuf, BT, HEADS * DK, CDIM, 1.0f, nullptr);
  gemm_kernel<<<dim3(BT / BM, (HEADS * DV) / BN), 256, 0, stream>>>(
      x, Wv, vbuf, BT, HEADS * DV, CDIM, 1.0f, nullptr);

  // relative-position keys
  rk_kernel<<<RWIN, 512, 0, stream>>>(Wrk, rkb);

  // fused attention
  attn_kernel<<<dim3(T_SEQ / QI, HEADS, 2), 256, 0, stream>>>(
      q, kbuf, vbuf, rkb, rwb, rrb, attn);

  // output projection + bias
  gemm_kernel<<<dim3(BT / BM, (HEADS * DV) / BN), 256, 0, stream>>>(
      attn, Wo, out, BT, HEADS * DV, CDIM, 1.0f, bo);
}

// Round 6
// 1089.475 us; speedup vs baseline: 2.3982x; 2.3982x over previous
//
#include <hip/hip_runtime.h>
#include <hip/hip_bf16.h>
#include <math.h>

// Problem constants (from reference)
#define T_SEQ 1536
#define CDIM  1536
#define HEADS 8
#define DK    64
#define DV    192
#define HK    (HEADS * DK)    // 512
#define HV    (HEADS * DV)    // 1536
#define RWIN  (2 * T_SEQ - 1) // 3071
#define QI    4               // query rows per attention block

typedef __attribute__((ext_vector_type(8))) short bf16x8;
typedef __attribute__((ext_vector_type(4))) float f32x4;

__device__ __forceinline__ unsigned short f2bf(float v) {
  __hip_bfloat16 h = __float2bfloat16(v);
  return *reinterpret_cast<unsigned short*>(&h);
}

// ---------------------------------------------------------------------------
// Elementwise fp32 -> bf16 cast. n multiple of 1024. 4 elems/thread.
// ---------------------------------------------------------------------------
__global__ __launch_bounds__(256) void cast_bf16_kernel(
    const float* __restrict__ in, unsigned short* __restrict__ out, int n)
{
  const int i = (blockIdx.x * 256 + threadIdx.x) * 4;
  if (i >= n) return;
  const float4 v = *reinterpret_cast<const float4*>(&in[i]);
  ushort4 o;
  o.x = f2bf(v.x); o.y = f2bf(v.y); o.z = f2bf(v.z); o.w = f2bf(v.w);
  *reinterpret_cast<ushort4*>(&out[i]) = o;
}

// ---------------------------------------------------------------------------
// Transpose-cast: W[Kd][N] fp32 -> Wt[N][Kd] bf16. Dims multiples of 32.
// Block (32,8), grid (N/32, Kd/32).
// ---------------------------------------------------------------------------
__global__ __launch_bounds__(256) void tcast_kernel(
    const float* __restrict__ W, unsigned short* __restrict__ Wt, int Kd, int N)
{
  __shared__ float tile[32][33];
  const int n0 = blockIdx.x * 32, k0 = blockIdx.y * 32;
  const int tx = threadIdx.x, ty = threadIdx.y;
  #pragma unroll
  for (int i = 0; i < 32; i += 8)
    tile[ty + i][tx] = W[(size_t)(k0 + ty + i) * N + n0 + tx];
  __syncthreads();
  #pragma unroll
  for (int i = 0; i < 32; i += 8)
    Wt[(size_t)(n0 + ty + i) * Kd + k0 + tx] = f2bf(tile[tx][ty + i]);
}

// ---------------------------------------------------------------------------
// bf16 MFMA GEMM: C[M,N] = scale*(A @ Bt^T) (+bias). A[M][Kd], Bt[N][Kd] bf16.
// 128x128 tile, BK=32, 256 thr = 2x2 waves, each wave 64x64 = 4x4 frags of
// 16x16x32. LDS pitch 40 elems (80 B rows) -> near-uniform bank spread.
// Register-prefetch rotation (R3-validated schedule): LDS-write(cur) ->
// barrier -> issue loads(next) -> compute(cur); vmcnt wait covered by MFMAs.
// Fragment layout (gfx950, guide §3, m89/m91-verified): A lane: row=l&15,
// k=8*(l>>4)+e; B lane: col=l&15, same k; D lane: col=l&15, row=4*(l>>4)+reg.
// ---------------------------------------------------------------------------
__global__ __launch_bounds__(256) void gemm_bf16_kernel(
    const unsigned short* __restrict__ A, const unsigned short* __restrict__ Bt,
    float* __restrict__ C, int M, int N, int Kd, float scale,
    const float* __restrict__ bias)
{
  constexpr int LDK = 40;
  __shared__ unsigned short As[128 * LDK];
  __shared__ unsigned short Bs[128 * LDK];
  const int tid = threadIdx.x;
  const int lane = tid & 63, wave = tid >> 6;
  const int wr = wave >> 1, wc = wave & 1;
  const int m0 = blockIdx.x * 128, n0 = blockIdx.y * 128;

  const int lr = tid >> 2;             // staging row 0..63 (and +64)
  const int lc = (tid & 3) * 8;        // staging k-offset in elems

  const int frow = lane & 15;
  const int fk = (lane >> 4) * 8;

  f32x4 acc[4][4];
  #pragma unroll
  for (int i = 0; i < 4; ++i)
    #pragma unroll
    for (int j = 0; j < 4; ++j) acc[i][j] = (f32x4){0.f, 0.f, 0.f, 0.f};

  // prologue: first K-tile into registers
  uint4 a0 = *reinterpret_cast<const uint4*>(&A[(size_t)(m0 + lr) * Kd + lc]);
  uint4 a1 = *reinterpret_cast<const uint4*>(&A[(size_t)(m0 + 64 + lr) * Kd + lc]);
  uint4 b0 = *reinterpret_cast<const uint4*>(&Bt[(size_t)(n0 + lr) * Kd + lc]);
  uint4 b1 = *reinterpret_cast<const uint4*>(&Bt[(size_t)(n0 + 64 + lr) * Kd + lc]);

  for (int k0 = 0; k0 < Kd; k0 += 32) {
    __syncthreads();                   // previous iteration's LDS reads done
    *reinterpret_cast<uint4*>(&As[lr * LDK + lc]) = a0;
    *reinterpret_cast<uint4*>(&As[(64 + lr) * LDK + lc]) = a1;
    *reinterpret_cast<uint4*>(&Bs[lr * LDK + lc]) = b0;
    *reinterpret_cast<uint4*>(&Bs[(64 + lr) * LDK + lc]) = b1;
    __syncthreads();
    if (k0 + 32 < Kd) {                // issue next tile's loads before compute
      const int kn = k0 + 32;
      a0 = *reinterpret_cast<const uint4*>(&A[(size_t)(m0 + lr) * Kd + kn + lc]);
      a1 = *reinterpret_cast<const uint4*>(&A[(size_t)(m0 + 64 + lr) * Kd + kn + lc]);
      b0 = *reinterpret_cast<const uint4*>(&Bt[(size_t)(n0 + lr) * Kd + kn + lc]);
      b1 = *reinterpret_cast<const uint4*>(&Bt[(size_t)(n0 + 64 + lr) * Kd + kn + lc]);
    }
    bf16x8 af[4], bfr[4];
    #pragma unroll
    for (int mi = 0; mi < 4; ++mi)
      af[mi] = *reinterpret_cast<const bf16x8*>(&As[(wr * 64 + mi * 16 + frow) * LDK + fk]);
    #pragma unroll
    for (int ni = 0; ni < 4; ++ni)
      bfr[ni] = *reinterpret_cast<const bf16x8*>(&Bs[(wc * 64 + ni * 16 + frow) * LDK + fk]);
    #pragma unroll
    for (int mi = 0; mi < 4; ++mi)
      #pragma unroll
      for (int ni = 0; ni < 4; ++ni)
        acc[mi][ni] = __builtin_amdgcn_mfma_f32_16x16x32_bf16(af[mi], bfr[ni], acc[mi][ni], 0, 0, 0);
  }

  const int er = (lane >> 4) * 4;
  #pragma unroll
  for (int mi = 0; mi < 4; ++mi)
    #pragma unroll
    for (int ni = 0; ni < 4; ++ni) {
      #pragma unroll
      for (int r = 0; r < 4; ++r) {
        const int m = m0 + wr * 64 + mi * 16 + er + r;
        const int n = n0 + wc * 64 + ni * 16 + frow;
        float v = acc[mi][ni][r] * scale;
        if (bias != nullptr) v += bias[n];
        C[(size_t)m * N + n] = v;
      }
    }
}

// ---------------------------------------------------------------------------
// r_k[h][r][kk] = sum_f pos[r,f] * Wrk[f, h*64+kk]  (fp32, tiny)
// ---------------------------------------------------------------------------
__global__ __launch_bounds__(512) void rk_kernel(
    const float* __restrict__ Wrk, float* __restrict__ rk)
{
  const int r = blockIdx.x;          // 0..3070
  const int t = threadIdx.x;         // 0..511
  __shared__ float pos[2 * 32];

  if (t < 64) {
    const double d = (double)(r - (T_SEQ - 1));
    const int j = t & 31;
    const double pr = exp(log((double)(T_SEQ + 1)) / 32.0);
    const double w = pow(pr, (double)(j + 1)) - 1.0;
    const float emb = (w > fabs(d)) ? 1.0f : 0.0f;
    const float sgn = (d > 0.0) ? 1.f : ((d < 0.0) ? -1.f : 0.f);
    pos[t] = (t < 32) ? emb : sgn * emb;
  }
  __syncthreads();

  float acc = 0.f;
  #pragma unroll 8
  for (int f = 0; f < 64; ++f) acc = fmaf(pos[f], Wrk[f * HK + t], acc);

  const int h = t >> 6, kk = t & 63;
  rk[((size_t)h * RWIN + r) * DK + kk] = acc;
}

// ---------------------------------------------------------------------------
// Fused attention (fp32 compute, bf16 output for the Wo GEMM).
// Block = (i-tile QI=4 rows, h, b); 256 threads.
// logits[i,j] = (q_i+rwb)·k_j + (q_i+rrb)·rk[j-i+T-1].
// launch_bounds(256,4): cap VGPR<=128 (R3 had 256 VGPR + 255MB spill writes).
// unroll 2 on kq loops: bounds the q-LDS-read hoist window.
// ---------------------------------------------------------------------------
__global__ __launch_bounds__(256, 4) void attn_kernel(
    const float* __restrict__ q, const float* __restrict__ kbuf,
    const float* __restrict__ vbuf, const float* __restrict__ rkbuf,
    const float* __restrict__ rwb, const float* __restrict__ rrb,
    unsigned short* __restrict__ outbf)
{
  const int it = blockIdx.x, h = blockIdx.y, b = blockIdx.z;
  const int i0 = it * QI;
  const int tid = threadIdx.x;

  __shared__ float qw[QI][DK];
  __shared__ float qr[QI][DK];
  __shared__ float sc[QI][T_SEQ];        // 24 KB
  __shared__ float part[4][QI][DV];      // 12 KB
  __shared__ float rinv[QI];

  if (tid < QI * DK) {
    const int row = tid >> 6, kk = tid & 63;
    const float qv = q[(size_t)(b * T_SEQ + i0 + row) * HK + h * DK + kk];
    qw[row][kk] = qv + rwb[h * DK + kk];
    qr[row][kk] = qv + rrb[h * DK + kk];
  }
  __syncthreads();

  // ---- content: thread owns column j, all 4 rows ----
  for (int jt = 0; jt < T_SEQ / 256; ++jt) {
    const int j = jt * 256 + tid;
    const float4* krow = reinterpret_cast<const float4*>(
        &kbuf[(size_t)(b * T_SEQ + j) * HK + h * DK]);
    float a0 = 0, a1 = 0, a2 = 0, a3 = 0;
    #pragma unroll 2
    for (int kq = 0; kq < DK / 4; ++kq) {
      const float4 kv = krow[kq];
      const float4 q0 = *reinterpret_cast<const float4*>(&qw[0][kq * 4]);
      const float4 q1 = *reinterpret_cast<const float4*>(&qw[1][kq * 4]);
      const float4 q2 = *reinterpret_cast<const float4*>(&qw[2][kq * 4]);
      const float4 q3 = *reinterpret_cast<const float4*>(&qw[3][kq * 4]);
      a0 = fmaf(q0.x, kv.x, fmaf(q0.y, kv.y, fmaf(q0.z, kv.z, fmaf(q0.w, kv.w, a0))));
      a1 = fmaf(q1.x, kv.x, fmaf(q1.y, kv.y, fmaf(q1.z, kv.z, fmaf(q1.w, kv.w, a1))));
      a2 = fmaf(q2.x, kv.x, fmaf(q2.y, kv.y, fmaf(q2.z, kv.z, fmaf(q2.w, kv.w, a2))));
      a3 = fmaf(q3.x, kv.x, fmaf(q3.y, kv.y, fmaf(q3.z, kv.z, fmaf(q3.w, kv.w, a3))));
    }
    sc[0][j] = a0; sc[1][j] = a1; sc[2][j] = a2; sc[3][j] = a3;
  }
  __syncthreads();

  // ---- rel: thread owns window index rt; r = (T-1)-(i0+QI-1)+rt ----
  const int WIN = T_SEQ + QI - 1;    // 1539
  for (int rt = tid; rt < WIN; rt += 256) {
    const int rr = (T_SEQ - 1) - (i0 + QI - 1) + rt;
    const float4* rkrow = reinterpret_cast<const float4*>(
        &rkbuf[((size_t)h * RWIN + rr) * DK]);
    float a0 = 0, a1 = 0, a2 = 0, a3 = 0;
    #pragma unroll 2
    for (int kq = 0; kq < DK / 4; ++kq) {
      const float4 rv = rkrow[kq];
      const float4 q0 = *reinterpret_cast<const float4*>(&qr[0][kq * 4]);
      const float4 q1 = *reinterpret_cast<const float4*>(&qr[1][kq * 4]);
      const float4 q2 = *reinterpret_cast<const float4*>(&qr[2][kq * 4]);
      const float4 q3 = *reinterpret_cast<const float4*>(&qr[3][kq * 4]);
      a0 = fmaf(q0.x, rv.x, fmaf(q0.y, rv.y, fmaf(q0.z, rv.z, fmaf(q0.w, rv.w, a0))));
      a1 = fmaf(q1.x, rv.x, fmaf(q1.y, rv.y, fmaf(q1.z, rv.z, fmaf(q1.w, rv.w, a1))));
      a2 = fmaf(q2.x, rv.x, fmaf(q2.y, rv.y, fmaf(q2.z, rv.z, fmaf(q2.w, rv.w, a2))));
      a3 = fmaf(q3.x, rv.x, fmaf(q3.y, rv.y, fmaf(q3.z, rv.z, fmaf(q3.w, rv.w, a3))));
    }
    const int jb = rt - (QI - 1);
    if (jb + 0 >= 0 && jb + 0 < T_SEQ) sc[0][jb + 0] += a0;
    if (jb + 1 >= 0 && jb + 1 < T_SEQ) sc[1][jb + 1] += a1;
    if (jb + 2 >= 0 && jb + 2 < T_SEQ) sc[2][jb + 2] += a2;
    if (jb + 3 >= 0 && jb + 3 < T_SEQ) sc[3][jb + 3] += a3;
  }
  __syncthreads();

  // ---- softmax: wave w handles row w ----
  {
    const int row = tid >> 6, lane = tid & 63;
    float m = -INFINITY;
    for (int j = lane; j < T_SEQ; j += 64) m = fmaxf(m, sc[row][j]);
    #pragma unroll
    for (int off = 32; off; off >>= 1) m = fmaxf(m, __shfl_xor(m, off));
    float s = 0.f;
    for (int j = lane; j < T_SEQ; j += 64) {
      const float e = __expf(sc[row][j] - m);
      sc[row][j] = e;
      s += e;
    }
    #pragma unroll
    for (int off = 32; off; off >>= 1) s += __shfl_xor(s, off);
    if (lane == 0) rinv[row] = 1.f / s;
  }
  __syncthreads();

  // ---- PV: wave w owns j-quarter; lane owns channels {lane, lane+64, lane+128}
  // (coalesced 256B v loads); sc reads are wave-uniform broadcasts.
  {
    const int w = tid >> 6, lane = tid & 63;
    const int j0 = w * (T_SEQ / 4);
    const float* vbase = &vbuf[(size_t)(b * T_SEQ + j0) * HV + h * DV];
    float a00 = 0, a01 = 0, a02 = 0;
    float a10 = 0, a11 = 0, a12 = 0;
    float a20 = 0, a21 = 0, a22 = 0;
    float a30 = 0, a31 = 0, a32 = 0;
    for (int jj = 0; jj < T_SEQ / 4; ++jj) {
      const float* vp = vbase + (size_t)jj * HV;
      const float v0 = vp[lane], v1 = vp[lane + 64], v2 = vp[lane + 128];
      const float w0 = sc[0][j0 + jj], w1 = sc[1][j0 + jj];
      const float w2 = sc[2][j0 + jj], w3 = sc[3][j0 + jj];
      a00 = fmaf(w0, v0, a00); a01 = fmaf(w0, v1, a01); a02 = fmaf(w0, v2, a02);
      a10 = fmaf(w1, v0, a10); a11 = fmaf(w1, v1, a11); a12 = fmaf(w1, v2, a12);
      a20 = fmaf(w2, v0, a20); a21 = fmaf(w2, v1, a21); a22 = fmaf(w2, v2, a22);
      a30 = fmaf(w3, v0, a30); a31 = fmaf(w3, v1, a31); a32 = fmaf(w3, v2, a32);
    }
    part[w][0][lane] = a00; part[w][0][lane + 64] = a01; part[w][0][lane + 128] = a02;
    part[w][1][lane] = a10; part[w][1][lane + 64] = a11; part[w][1][lane + 128] = a12;
    part[w][2][lane] = a20; part[w][2][lane + 64] = a21; part[w][2][lane + 128] = a22;
    part[w][3][lane] = a30; part[w][3][lane + 64] = a31; part[w][3][lane + 128] = a32;
  }
  __syncthreads();

  for (int o = tid; o < QI * DV; o += 256) {
    const int r = o / DV, c = o % DV;
    const float s = part[0][r][c] + part[1][r][c] + part[2][r][c] + part[3][r][c];
    outbf[(size_t)(b * T_SEQ + i0 + r) * HV + h * DV + c] = f2bf(s * rinv[r]);
  }
}

// ---------------------------------------------------------------------------
extern "C" void kernel_launch(void* const* d_in, const int* in_sizes, int n_in,
                              void* d_out, int out_size, void* d_ws, size_t ws_size,
                              hipStream_t stream) {
  const float* x   = (const float*)d_in[0];
  const float* Wq  = (const float*)d_in[1];
  const float* Wk  = (const float*)d_in[2];
  const float* Wv  = (const float*)d_in[3];
  const float* Wrk = (const float*)d_in[4];
  const float* rwb = (const float*)d_in[5];
  const float* rrb = (const float*)d_in[6];
  const float* Wo  = (const float*)d_in[7];
  const float* bo  = (const float*)d_in[8];
  float* out = (float*)d_out;

  const int BT = 2 * T_SEQ;   // 3072

  // Workspace (56,621,056 B total — identical to the proven R3 footprint):
  // [qf 6.29M][kf 6.29M][vf 18.87M][rk 6.29M][xb/abf 9.44M][Wot 4.72M][U 4.72M]
  // U holds Wqt+Wkt first, then is overwritten by Wvt (after the k GEMM).
  char* w = (char*)d_ws;
  float* qf  = (float*)w;  w += (size_t)BT * HK * 4;          // 6,291,456
  float* kf  = (float*)w;  w += (size_t)BT * HK * 4;          // 6,291,456
  float* vf  = (float*)w;  w += (size_t)BT * HV * 4;          // 18,874,368
  float* rkb = (float*)w;  w += (size_t)HEADS * RWIN * DK * 4;// 6,289,408
  unsigned short* xb  = (unsigned short*)w; w += (size_t)BT * CDIM * 2; // 9,437,184
  unsigned short* Wot = (unsigned short*)w; w += (size_t)HV * CDIM * 2; // 4,718,592
  unsigned short* Wqt = (unsigned short*)w;                   // U region
  unsigned short* Wkt = Wqt + (size_t)HK * CDIM;              // U + 1,572,864 B
  unsigned short* Wvt = Wqt;                                  // reuses U

  const int nx = BT * CDIM;   // 4,718,592

  // casts + projections
  cast_bf16_kernel<<<nx / 1024, 256, 0, stream>>>(x, xb, nx);
  tcast_kernel<<<dim3(HK / 32, CDIM / 32), dim3(32, 8), 0, stream>>>(Wq, Wqt, CDIM, HK);
  tcast_kernel<<<dim3(HK / 32, CDIM / 32), dim3(32, 8), 0, stream>>>(Wk, Wkt, CDIM, HK);
  gemm_bf16_kernel<<<dim3(BT / 128, HK / 128), 256, 0, stream>>>(
      xb, Wqt, qf, BT, HK, CDIM, 0.125f, nullptr);
  gemm_bf16_kernel<<<dim3(BT / 128, HK / 128), 256, 0, stream>>>(
      xb, Wkt, kf, BT, HK, CDIM, 1.0f, nullptr);
  tcast_kernel<<<dim3(HV / 32, CDIM / 32), dim3(32, 8), 0, stream>>>(Wv, Wvt, CDIM, HV);
  gemm_bf16_kernel<<<dim3(BT / 128, HV / 128), 256, 0, stream>>>(
      xb, Wvt, vf, BT, HV, CDIM, 1.0f, nullptr);

  rk_kernel<<<RWIN, 512, 0, stream>>>(Wrk, rkb);
  tcast_kernel<<<dim3(HV / 32, CDIM / 32), dim3(32, 8), 0, stream>>>(Wo, Wot, CDIM, HV);

  // attention (writes bf16 into xb region — x is dead after the v GEMM)
  attn_kernel<<<dim3(T_SEQ / QI, HEADS, 2), 256, 0, stream>>>(
      qf, kf, vf, rkb, rwb, rrb, xb);

  // output projection + bias
  gemm_bf16_kernel<<<dim3(BT / 128, HV / 128), 256, 0, stream>>>(
      xb, Wot, out, BT, HV, CDIM, 1.0f, bo);
}

// Round 8
// 417.259 us; speedup vs baseline: 6.2617x; 2.6110x over previous
//
#include <hip/hip_runtime.h>
#include <hip/hip_bf16.h>
#include <math.h>

// Problem constants (from reference)
#define T_SEQ 1536
#define CDIM  1536
#define HEADS 8
#define DK    64
#define DV    192
#define HK    (HEADS * DK)    // 512
#define HV    (HEADS * DV)    // 1536
#define RWIN  (2 * T_SEQ - 1) // 3071

typedef __attribute__((ext_vector_type(8))) short bf16x8;
typedef __attribute__((ext_vector_type(4))) float f32x4;

__device__ __forceinline__ unsigned short f2bf(float v) {
  __hip_bfloat16 h = __float2bfloat16(v);
  return *reinterpret_cast<unsigned short*>(&h);
}
__device__ __forceinline__ float bf2f(unsigned short u) {
  unsigned int x = ((unsigned int)u) << 16;
  union { unsigned int i; float f; } c; c.i = x; return c.f;
}

// ---------------------------------------------------------------------------
// Elementwise fp32 -> bf16 cast. n multiple of 1024.
// ---------------------------------------------------------------------------
__global__ __launch_bounds__(256) void cast_bf16_kernel(
    const float* __restrict__ in, unsigned short* __restrict__ out, int n)
{
  const int i = (blockIdx.x * 256 + threadIdx.x) * 4;
  if (i >= n) return;
  const float4 v = *reinterpret_cast<const float4*>(&in[i]);
  ushort4 o;
  o.x = f2bf(v.x); o.y = f2bf(v.y); o.z = f2bf(v.z); o.w = f2bf(v.w);
  *reinterpret_cast<ushort4*>(&out[i]) = o;
}

// ---------------------------------------------------------------------------
// Transpose-cast: W[Kd][N] fp32 -> Wt[N][Kd] bf16.
// ---------------------------------------------------------------------------
__global__ __launch_bounds__(256) void tcast_kernel(
    const float* __restrict__ W, unsigned short* __restrict__ Wt, int Kd, int N)
{
  __shared__ float tile[32][33];
  const int n0 = blockIdx.x * 32, k0 = blockIdx.y * 32;
  const int tx = threadIdx.x, ty = threadIdx.y;
  #pragma unroll
  for (int i = 0; i < 32; i += 8)
    tile[ty + i][tx] = W[(size_t)(k0 + ty + i) * N + n0 + tx];
  __syncthreads();
  #pragma unroll
  for (int i = 0; i < 32; i += 8)
    Wt[(size_t)(n0 + ty + i) * Kd + k0 + tx] = f2bf(tile[tx][ty + i]);
}

// ---------------------------------------------------------------------------
// bf16 MFMA GEMM (R6 HW-validated body). OMODE 0: f32 out (+bias);
// 1: bf16 out; 2: bf16 transposed out vt[b][n][t] (for V).
// ---------------------------------------------------------------------------
template<int OMODE>
__global__ __launch_bounds__(256) void gemm_bf16_kernel(
    const unsigned short* __restrict__ A, const unsigned short* __restrict__ Bt,
    void* __restrict__ Cp, int M, int N, int Kd, float scale,
    const float* __restrict__ bias)
{
  constexpr int LDK = 40;
  __shared__ unsigned short As[128 * LDK];
  __shared__ unsigned short Bs[128 * LDK];
  const int tid = threadIdx.x;
  const int lane = tid & 63, wave = tid >> 6;
  const int wr = wave >> 1, wc = wave & 1;
  const int m0 = blockIdx.x * 128, n0 = blockIdx.y * 128;

  const int lr = tid >> 2;
  const int lc = (tid & 3) * 8;
  const int frow = lane & 15;
  const int fk = (lane >> 4) * 8;

  f32x4 acc[4][4];
  #pragma unroll
  for (int i = 0; i < 4; ++i)
    #pragma unroll
    for (int j = 0; j < 4; ++j) acc[i][j] = (f32x4){0.f, 0.f, 0.f, 0.f};

  uint4 a0 = *reinterpret_cast<const uint4*>(&A[(size_t)(m0 + lr) * Kd + lc]);
  uint4 a1 = *reinterpret_cast<const uint4*>(&A[(size_t)(m0 + 64 + lr) * Kd + lc]);
  uint4 b0 = *reinterpret_cast<const uint4*>(&Bt[(size_t)(n0 + lr) * Kd + lc]);
  uint4 b1 = *reinterpret_cast<const uint4*>(&Bt[(size_t)(n0 + 64 + lr) * Kd + lc]);

  for (int k0 = 0; k0 < Kd; k0 += 32) {
    __syncthreads();
    *reinterpret_cast<uint4*>(&As[lr * LDK + lc]) = a0;
    *reinterpret_cast<uint4*>(&As[(64 + lr) * LDK + lc]) = a1;
    *reinterpret_cast<uint4*>(&Bs[lr * LDK + lc]) = b0;
    *reinterpret_cast<uint4*>(&Bs[(64 + lr) * LDK + lc]) = b1;
    __syncthreads();
    if (k0 + 32 < Kd) {
      const int kn = k0 + 32;
      a0 = *reinterpret_cast<const uint4*>(&A[(size_t)(m0 + lr) * Kd + kn + lc]);
      a1 = *reinterpret_cast<const uint4*>(&A[(size_t)(m0 + 64 + lr) * Kd + kn + lc]);
      b0 = *reinterpret_cast<const uint4*>(&Bt[(size_t)(n0 + lr) * Kd + kn + lc]);
      b1 = *reinterpret_cast<const uint4*>(&Bt[(size_t)(n0 + 64 + lr) * Kd + kn + lc]);
    }
    bf16x8 af[4], bfr[4];
    #pragma unroll
    for (int mi = 0; mi < 4; ++mi)
      af[mi] = *reinterpret_cast<const bf16x8*>(&As[(wr * 64 + mi * 16 + frow) * LDK + fk]);
    #pragma unroll
    for (int ni = 0; ni < 4; ++ni)
      bfr[ni] = *reinterpret_cast<const bf16x8*>(&Bs[(wc * 64 + ni * 16 + frow) * LDK + fk]);
    #pragma unroll
    for (int mi = 0; mi < 4; ++mi)
      #pragma unroll
      for (int ni = 0; ni < 4; ++ni)
        acc[mi][ni] = __builtin_amdgcn_mfma_f32_16x16x32_bf16(af[mi], bfr[ni], acc[mi][ni], 0, 0, 0);
  }

  const int er = (lane >> 4) * 4;
  #pragma unroll
  for (int mi = 0; mi < 4; ++mi)
    #pragma unroll
    for (int ni = 0; ni < 4; ++ni) {
      const int n = n0 + wc * 64 + ni * 16 + frow;
      if constexpr (OMODE == 2) {
        // pack 4 consecutive t (= m rows) into ushort4 at vt[b][n][t0]
        const int mrow0 = m0 + wr * 64 + mi * 16 + er;
        const int bb = mrow0 / T_SEQ;
        const int t0 = mrow0 - bb * T_SEQ;
        ushort4 pk;
        pk.x = f2bf(acc[mi][ni][0] * scale);
        pk.y = f2bf(acc[mi][ni][1] * scale);
        pk.z = f2bf(acc[mi][ni][2] * scale);
        pk.w = f2bf(acc[mi][ni][3] * scale);
        *reinterpret_cast<ushort4*>(
            &((unsigned short*)Cp)[((size_t)bb * HV + n) * T_SEQ + t0]) = pk;
      } else {
        #pragma unroll
        for (int r = 0; r < 4; ++r) {
          const int m = m0 + wr * 64 + mi * 16 + er + r;
          float v = acc[mi][ni][r] * scale;
          if constexpr (OMODE == 0) {
            if (bias != nullptr) v += bias[n];
            ((float*)Cp)[(size_t)m * N + n] = v;
          } else {
            ((unsigned short*)Cp)[(size_t)m * N + n] = f2bf(v);
          }
        }
      }
    }
}

// ---------------------------------------------------------------------------
// r_k (bf16 out): rk[h][r][kk] = sum_f pos[r,f] * Wrk[f, h*64+kk]
// ---------------------------------------------------------------------------
__global__ __launch_bounds__(512) void rk_kernel(
    const float* __restrict__ Wrk, unsigned short* __restrict__ rk)
{
  const int r = blockIdx.x;
  const int t = threadIdx.x;
  __shared__ float pos[64];

  if (t < 64) {
    const double d = (double)(r - (T_SEQ - 1));
    const int j = t & 31;
    const double pr = exp(log((double)(T_SEQ + 1)) / 32.0);
    const double w = pow(pr, (double)(j + 1)) - 1.0;
    const float emb = (w > fabs(d)) ? 1.0f : 0.0f;
    const float sgn = (d > 0.0) ? 1.f : ((d < 0.0) ? -1.f : 0.f);
    pos[t] = (t < 32) ? emb : sgn * emb;
  }
  __syncthreads();

  float acc = 0.f;
  #pragma unroll 8
  for (int f = 0; f < 64; ++f) acc = fmaf(pos[f], Wrk[f * HK + t], acc);

  const int h = t >> 6, kk = t & 63;
  rk[((size_t)h * RWIN + r) * DK + kk] = f2bf(acc);
}

// ---------------------------------------------------------------------------
// MFMA flash attention. Block = (64-row q-tile, h, b); 4 waves (256 thr).
// logits[i,j] = (q+rwb)_i·k_j + (q+rrb)_i·rk[j-i+T-1] (shift collapsed).
// Wave owns 16 q-rows. Per kv-tile (64): content 8 MFMA, rel 8 MFMA into a
// 128-slot sliding ring (band advances by exactly 64/tile), gather-add,
// in-register online softmax (rows of S/O frags share lane mapping), PV 24
// MFMA from P_lds x V^T_lds. Fragment layouts = R6 HW-validated GEMM ones.
// ---------------------------------------------------------------------------
__global__ __launch_bounds__(256, 2) void attn_mfma_kernel(
    const float* __restrict__ qf, const unsigned short* __restrict__ kb,
    const unsigned short* __restrict__ vt, const unsigned short* __restrict__ rkb,
    const float* __restrict__ rwb, const float* __restrict__ rrb,
    unsigned short* __restrict__ ab)
{
  const int it = blockIdx.x, h = blockIdx.y, b = blockIdx.z;
  const int i0 = it * 64;
  const int tid = threadIdx.x, lane = tid & 63, wv = tid >> 6;
  const int cl = lane & 15, g4 = 4 * (lane >> 4), kb8 = 8 * (lane >> 4);

  __shared__ unsigned short Klds[64][72];    //  9216 B
  __shared__ unsigned short Vlds[192][72];   // 27648 B
  __shared__ unsigned short Rbuf[64][132];   // 16896 B (128-slot ring + pad)
  __shared__ unsigned short Plds[64][72];    //  9216 B

  // ---- Q fragments (A-layout: row=lane&15 within wave's 16, k=8*(lane>>4)+e)
  bf16x8 qwf[2], qrf[2];
  {
    const int qrow = b * T_SEQ + i0 + 16 * wv + cl;
    const float* qp = &qf[(size_t)qrow * HK + h * DK];
    #pragma unroll
    for (int kf = 0; kf < 2; ++kf) {
      bf16x8 tw, tr;
      #pragma unroll
      for (int e = 0; e < 8; ++e) {
        const int k = kb8 + 32 * kf + e;
        const float qv = qp[k];                  // already scaled by 0.125
        tw[e] = (short)f2bf(qv + rwb[h * DK + k]);
        tr[e] = (short)f2bf(qv + rrb[h * DK + k]);
      }
      qwf[kf] = tw; qrf[kf] = tr;
    }
  }

  // ---- staging (register-prefetch rotation, R6-validated) ----
  uint4 kreg[2], vreg[6];
  auto load_tiles = [&](int j0) {
    #pragma unroll
    for (int c = 0; c < 2; ++c) {
      const int idx = tid + 256 * c;
      kreg[c] = *reinterpret_cast<const uint4*>(
          &kb[((size_t)(b * T_SEQ + j0 + (idx >> 3))) * HK + h * DK + (idx & 7) * 8]);
    }
    #pragma unroll
    for (int c = 0; c < 6; ++c) {
      const int idx = tid + 256 * c;
      vreg[c] = *reinterpret_cast<const uint4*>(
          &vt[((size_t)b * HV + h * DV + (idx >> 3)) * T_SEQ + j0 + (idx & 7) * 8]);
    }
  };
  auto store_tiles = [&]() {
    #pragma unroll
    for (int c = 0; c < 2; ++c) {
      const int idx = tid + 256 * c;
      *reinterpret_cast<uint4*>(&Klds[idx >> 3][(idx & 7) * 8]) = kreg[c];
    }
    #pragma unroll
    for (int c = 0; c < 6; ++c) {
      const int idx = tid + 256 * c;
      *reinterpret_cast<uint4*>(&Vlds[idx >> 3][(idx & 7) * 8]) = vreg[c];
    }
  };

  // ---- rel band (64 cols at rk rows [base, base+64)) -> ring ----
  auto computeR = [&](int base) {
    #pragma unroll
    for (int f = 0; f < 4; ++f) {
      f32x4 rr = (f32x4){0.f, 0.f, 0.f, 0.f};
      #pragma unroll
      for (int ks = 0; ks < 2; ++ks) {
        int row = base + 16 * f + cl;
        row = row < 0 ? 0 : row;                 // rho=-1 slot written, never read
        const bf16x8 bfrag = *reinterpret_cast<const bf16x8*>(
            &rkb[((size_t)h * RWIN + row) * DK + kb8 + 32 * ks]);
        rr = __builtin_amdgcn_mfma_f32_16x16x32_bf16(qrf[ks], bfrag, rr, 0, 0, 0);
      }
      const int irow = 16 * wv + g4;
      const int slot = (base + 16 * f + cl) & 127;
      #pragma unroll
      for (int r = 0; r < 4; ++r)
        Rbuf[irow + r][slot] = f2bf(rr[r]);
    }
  };

  float mrun[4] = {-1e30f, -1e30f, -1e30f, -1e30f};
  float lrun[4] = {0.f, 0.f, 0.f, 0.f};
  f32x4 o[12];
  #pragma unroll
  for (int vf = 0; vf < 12; ++vf) o[vf] = (f32x4){0.f, 0.f, 0.f, 0.f};

  const int D0 = T_SEQ - 1 - i0;
  load_tiles(0);
  computeR(D0 - 64);                             // prologue band (wave-local LDS)
  int Dj = D0;

  for (int jt = 0; jt < T_SEQ / 64; ++jt) {
    __syncthreads();                             // all waves done with prev tiles
    store_tiles();
    __syncthreads();
    if (jt + 1 < T_SEQ / 64) load_tiles((jt + 1) * 64);

    computeR(Dj);                                // new 64 ring cols [Dj, Dj+63]

    // content: S = qw @ K^T
    f32x4 s[4];
    #pragma unroll
    for (int f = 0; f < 4; ++f) {
      s[f] = (f32x4){0.f, 0.f, 0.f, 0.f};
      #pragma unroll
      for (int ks = 0; ks < 2; ++ks) {
        const bf16x8 kfrag = *reinterpret_cast<const bf16x8*>(
            &Klds[16 * f + cl][kb8 + 32 * ks]);
        s[f] = __builtin_amdgcn_mfma_f32_16x16x32_bf16(qwf[ks], kfrag, s[f], 0, 0, 0);
      }
    }
    // rel gather-add: rho = Dj + j' - i'
    #pragma unroll
    for (int f = 0; f < 4; ++f)
      #pragma unroll
      for (int r = 0; r < 4; ++r) {
        const int iloc = 16 * wv + g4 + r;
        const int slot = (Dj + 16 * f + cl - iloc) & 127;
        s[f][r] += bf2f(Rbuf[iloc][slot]);
      }
    // online softmax (rows lane-local across S and O frags)
    #pragma unroll
    for (int r = 0; r < 4; ++r) {
      float mx = fmaxf(fmaxf(s[0][r], s[1][r]), fmaxf(s[2][r], s[3][r]));
      mx = fmaxf(mx, __shfl_xor(mx, 1));
      mx = fmaxf(mx, __shfl_xor(mx, 2));
      mx = fmaxf(mx, __shfl_xor(mx, 4));
      mx = fmaxf(mx, __shfl_xor(mx, 8));
      const float mnew = fmaxf(mrun[r], mx);
      const float fac = __expf(mrun[r] - mnew);
      mrun[r] = mnew;
      float ps = 0.f;
      #pragma unroll
      for (int f = 0; f < 4; ++f) {
        const float p = __expf(s[f][r] - mnew);
        ps += p;
        Plds[16 * wv + g4 + r][16 * f + cl] = f2bf(p);
      }
      ps += __shfl_xor(ps, 1);
      ps += __shfl_xor(ps, 2);
      ps += __shfl_xor(ps, 4);
      ps += __shfl_xor(ps, 8);
      lrun[r] = lrun[r] * fac + ps;
      #pragma unroll
      for (int vf = 0; vf < 12; ++vf) o[vf][r] *= fac;
    }
    // PV: O += P @ V^T  (A=P rows=q-rows k=j'; B=Vt rows=v-cols k=j')
    #pragma unroll
    for (int ks = 0; ks < 2; ++ks) {
      const bf16x8 pfrag = *reinterpret_cast<const bf16x8*>(
          &Plds[16 * wv + cl][kb8 + 32 * ks]);
      #pragma unroll
      for (int vf = 0; vf < 12; ++vf) {
        const bf16x8 vfrag = *reinterpret_cast<const bf16x8*>(
            &Vlds[16 * vf + cl][kb8 + 32 * ks]);
        o[vf] = __builtin_amdgcn_mfma_f32_16x16x32_bf16(pfrag, vfrag, o[vf], 0, 0, 0);
      }
    }
    Dj += 64;
  }

  // epilogue: O / l -> ab bf16
  #pragma unroll
  for (int r = 0; r < 4; ++r) {
    const float inv = 1.f / lrun[r];
    const size_t gi = (size_t)(b * T_SEQ + i0 + 16 * wv + g4 + r);
    #pragma unroll
    for (int vf = 0; vf < 12; ++vf) {
      const int v = 16 * vf + cl;
      ab[gi * HV + h * DV + v] = f2bf(o[vf][r] * inv);
    }
  }
}

// ---------------------------------------------------------------------------
extern "C" void kernel_launch(void* const* d_in, const int* in_sizes, int n_in,
                              void* d_out, int out_size, void* d_ws, size_t ws_size,
                              hipStream_t stream) {
  const float* x   = (const float*)d_in[0];
  const float* Wq  = (const float*)d_in[1];
  const float* Wk  = (const float*)d_in[2];
  const float* Wv  = (const float*)d_in[3];
  const float* Wrk = (const float*)d_in[4];
  const float* rwb = (const float*)d_in[5];
  const float* rrb = (const float*)d_in[6];
  const float* Wo  = (const float*)d_in[7];
  const float* bo  = (const float*)d_in[8];
  float* out = (float*)d_out;

  const int BT = 2 * T_SEQ;   // 3072

  // Workspace: 53,476,352 B total (< 56.6 MB proven footprint)
  char* w = (char*)d_ws;
  float* qf           = (float*)w;          w += (size_t)BT * HK * 4;        // q (f32, scaled)
  unsigned short* kbuf = (unsigned short*)w; w += (size_t)BT * HK * 2;       // k bf16
  unsigned short* vtb  = (unsigned short*)w; w += (size_t)2 * HV * T_SEQ * 2;// V^T bf16 [b][v][t]
  unsigned short* rkb  = (unsigned short*)w; w += (size_t)HEADS * RWIN * DK * 2;
  unsigned short* xb   = (unsigned short*)w; w += (size_t)BT * CDIM * 2;
  unsigned short* ab   = (unsigned short*)w; w += (size_t)BT * HV * 2;
  unsigned short* Wqt  = (unsigned short*)w; w += (size_t)HK * CDIM * 2;
  unsigned short* Wkt  = (unsigned short*)w; w += (size_t)HK * CDIM * 2;
  unsigned short* Wvt  = (unsigned short*)w; w += (size_t)HV * CDIM * 2;
  unsigned short* Wot  = (unsigned short*)w; w += (size_t)HV * CDIM * 2;

  const int nx = BT * CDIM;

  cast_bf16_kernel<<<nx / 1024, 256, 0, stream>>>(x, xb, nx);
  tcast_kernel<<<dim3(HK / 32, CDIM / 32), dim3(32, 8), 0, stream>>>(Wq, Wqt, CDIM, HK);
  tcast_kernel<<<dim3(HK / 32, CDIM / 32), dim3(32, 8), 0, stream>>>(Wk, Wkt, CDIM, HK);
  tcast_kernel<<<dim3(HV / 32, CDIM / 32), dim3(32, 8), 0, stream>>>(Wv, Wvt, CDIM, HV);
  tcast_kernel<<<dim3(HV / 32, CDIM / 32), dim3(32, 8), 0, stream>>>(Wo, Wot, CDIM, HV);

  gemm_bf16_kernel<0><<<dim3(BT / 128, HK / 128), 256, 0, stream>>>(
      xb, Wqt, qf, BT, HK, CDIM, 0.125f, nullptr);
  gemm_bf16_kernel<1><<<dim3(BT / 128, HK / 128), 256, 0, stream>>>(
      xb, Wkt, kbuf, BT, HK, CDIM, 1.0f, nullptr);
  gemm_bf16_kernel<2><<<dim3(BT / 128, HV / 128), 256, 0, stream>>>(
      xb, Wvt, vtb, BT, HV, CDIM, 1.0f, nullptr);

  rk_kernel<<<RWIN, 512, 0, stream>>>(Wrk, rkb);

  attn_mfma_kernel<<<dim3(T_SEQ / 64, HEADS, 2), 256, 0, stream>>>(
      qf, kbuf, vtb, rkb, rwb, rrb, ab);

  gemm_bf16_kernel<0><<<dim3(BT / 128, HV / 128), 256, 0, stream>>>(
      ab, Wot, out, BT, HV, CDIM, 1.0f, bo);
}